// Round 1
// baseline (972.009 us; speedup 1.0000x reference)
//
#include <hip/hip_runtime.h>

// Problem constants (from reference): B=1048576, T=11, F=3, H=11, C=7
#define TT 11
#define FF 3
#define HH 11
#define CC 7
#define TH 33   // 3*H
#define TF 33   // T*F
#define BLOCK 256

__device__ __forceinline__ float fast_sigmoid(float a) {
    // 1/(1+exp(-a)) ; exp via exp2. a->-inf: rcp(inf)=0, a->+inf: 1. No NaN.
    float t = __builtin_amdgcn_exp2f(-1.44269504088896340736f * a);
    return __builtin_amdgcn_rcpf(1.0f + t);
}

__device__ __forceinline__ float fast_tanh(float a) {
    // (1-e^-2a)/(1+e^-2a); clamp to avoid inf*0 NaN on very negative a
    a = fmaxf(a, -30.0f);
    float t = __builtin_amdgcn_exp2f(-2.88539008177792681472f * a);
    return (1.0f - t) * __builtin_amdgcn_rcpf(1.0f + t);
}

__global__ __launch_bounds__(BLOCK, 4) void gru_dense_softmax(
    const float* __restrict__ x,     // [B, T, F]
    const float* __restrict__ kern,  // [F, 3H]
    const float* __restrict__ rk,    // [H, 3H]
    const float* __restrict__ bias,  // [2, 3H]
    const float* __restrict__ dw,    // [T*H, C]
    const float* __restrict__ db,    // [C]
    float* __restrict__ out,         // [B, C]
    int Bt)
{
    __shared__ float smem[BLOCK * TF];  // 33 KB; reused for output staging
    const int tid = threadIdx.x;
    const long long base = (long long)blockIdx.x * BLOCK;

    // ---- coalesced stage of this block's x tile into LDS ----
    {
        const long long gbase = base * TF;
        const long long gmax = (long long)Bt * TF;
        #pragma unroll
        for (int i = 0; i < TF; ++i) {
            long long g = gbase + tid + i * BLOCK;
            smem[tid + i * BLOCK] = (g < gmax) ? x[g] : 0.0f;
        }
    }
    __syncthreads();

    float h[HH];
    #pragma unroll
    for (int j = 0; j < HH; ++j) h[j] = 0.0f;
    float logit[CC];
    #pragma unroll
    for (int c = 0; c < CC; ++c) logit[c] = db[c];

    // per-thread x: stride 33 floats -> lane i hits bank (33*i)%32 = i%32,
    // conflict-free (2 lanes/bank for wave64 is free)
    const float* xv = &smem[tid * TF];

    #pragma unroll 1   // keep body ~6KB, inside I-cache; weights re-s_load per t (scalar $ hits)
    for (int t = 0; t < TT; ++t) {
        const float x0 = xv[t * FF + 0];
        const float x1 = xv[t * FF + 1];
        const float x2 = xv[t * FF + 2];

        float z[HH], hn[HH];

        // ---- z gate (cols 0..H-1); input+recurrent bias fold ----
        #pragma unroll
        for (int j = 0; j < HH; ++j) {
            float a = bias[j] + bias[TH + j];
            a = fmaf(x0, kern[0 * TH + j], a);
            a = fmaf(x1, kern[1 * TH + j], a);
            a = fmaf(x2, kern[2 * TH + j], a);
            #pragma unroll
            for (int i = 0; i < HH; ++i) a = fmaf(h[i], rk[i * TH + j], a);
            z[j] = fast_sigmoid(a);
        }

        // ---- r gate (cols H..2H-1) + candidate hh (cols 2H..3H-1) ----
        // reset_after=True: hh = tanh(xh + r * (h@rk_h + rec_b_h))
        #pragma unroll
        for (int j = 0; j < HH; ++j) {
            const int jr = HH + j;
            float a = bias[jr] + bias[TH + jr];
            a = fmaf(x0, kern[0 * TH + jr], a);
            a = fmaf(x1, kern[1 * TH + jr], a);
            a = fmaf(x2, kern[2 * TH + jr], a);
            #pragma unroll
            for (int i = 0; i < HH; ++i) a = fmaf(h[i], rk[i * TH + jr], a);
            const float r = fast_sigmoid(a);

            const int jh = 2 * HH + j;
            float xh = bias[jh];
            xh = fmaf(x0, kern[0 * TH + jh], xh);
            xh = fmaf(x1, kern[1 * TH + jh], xh);
            xh = fmaf(x2, kern[2 * TH + jh], xh);
            float rh = bias[TH + jh];
            #pragma unroll
            for (int i = 0; i < HH; ++i) rh = fmaf(h[i], rk[i * TH + jh], rh);
            hn[j] = fast_tanh(fmaf(r, rh, xh));
        }

        // ---- h update + fused dense accumulation (hs never materialized) ----
        #pragma unroll
        for (int j = 0; j < HH; ++j) {
            const float hnew = hn[j] + z[j] * (h[j] - hn[j]);  // z*h + (1-z)*hh
            h[j] = hnew;
            #pragma unroll
            for (int c = 0; c < CC; ++c)
                logit[c] = fmaf(hnew, dw[(t * HH + j) * CC + c], logit[c]);
        }
    }

    // ---- softmax (max-subtracted, matches jax.nn.softmax) ----
    float m = logit[0];
    #pragma unroll
    for (int c = 1; c < CC; ++c) m = fmaxf(m, logit[c]);
    float s = 0.0f;
    float e[CC];
    #pragma unroll
    for (int c = 0; c < CC; ++c) {
        e[c] = __builtin_amdgcn_exp2f((logit[c] - m) * 1.44269504088896340736f);
        s += e[c];
    }
    const float inv = __builtin_amdgcn_rcpf(s);

    // ---- staged coalesced writeback (reuse smem; barrier guards reuse) ----
    __syncthreads();
    #pragma unroll
    for (int c = 0; c < CC; ++c) smem[tid * CC + c] = e[c] * inv;  // stride 7: conflict-free
    __syncthreads();
    {
        const long long obase = base * CC;
        const long long omax = (long long)Bt * CC;
        #pragma unroll
        for (int i = 0; i < CC; ++i) {
            long long g = obase + tid + i * BLOCK;
            if (g < omax) out[g] = smem[tid + i * BLOCK];
        }
    }
}

extern "C" void kernel_launch(void* const* d_in, const int* in_sizes, int n_in,
                              void* d_out, int out_size, void* d_ws, size_t ws_size,
                              hipStream_t stream) {
    const float* x   = (const float*)d_in[0];
    const float* k   = (const float*)d_in[1];
    const float* rk  = (const float*)d_in[2];
    const float* bi  = (const float*)d_in[3];
    const float* dw  = (const float*)d_in[4];
    const float* db  = (const float*)d_in[5];
    float* out = (float*)d_out;

    const int Bt = in_sizes[0] / TF;            // 1048576
    const int grid = (Bt + BLOCK - 1) / BLOCK;  // 4096
    gru_dense_softmax<<<grid, BLOCK, 0, stream>>>(x, k, rk, bi, dw, db, out, Bt);
}

// Round 2
// 632.277 us; speedup vs baseline: 1.5373x; 1.5373x over previous
//
#include <hip/hip_runtime.h>

// Problem constants: B=1048576, T=11, F=3, H=11, C=7
#define TT 11
#define FF 3
#define HH 11
#define CC 7
#define TH 33   // 3*H
#define TF 33   // T*F
#define BLOCK 256
#define HP 12   // H padded to 6 float2 pairs
#define CP 8    // C padded to 4 float2 pairs

typedef float f2 __attribute__((ext_vector_type(2)));
typedef float f4 __attribute__((ext_vector_type(4)));

// workspace float offsets
#define WS_KX   0      // [33] float4: k0j,k1j,k2j,bias_sum_j
#define WS_RKP  132    // [33][12]: rkp[j][i] = rk[i][j], i-pad to 12
#define WS_RB   528    // [12]: recurrent bias for hh columns (pad 0)
#define WS_DWP  540    // [121][8]: dw padded C->8
#define WS_DBP  1508   // [8]
#define WS_TOT  1516

__device__ __forceinline__ float fast_sigmoid(float a) {
    float t = __builtin_amdgcn_exp2f(-1.44269504088896340736f * a);
    return __builtin_amdgcn_rcpf(1.0f + t);
}
// tanh(a) = 2*sigmoid(2a) - 1 ; limits: a->-inf -> -1, a->+inf -> +1, no NaN
__device__ __forceinline__ float fast_tanh(float a) {
    float t = __builtin_amdgcn_exp2f(-2.88539008177792681472f * a);
    return fmaf(2.0f, __builtin_amdgcn_rcpf(1.0f + t), -1.0f);
}

__global__ void prep_weights(const float* __restrict__ k,
                             const float* __restrict__ rk,
                             const float* __restrict__ bias,
                             const float* __restrict__ dw,
                             const float* __restrict__ db,
                             float* __restrict__ ws) {
    const int i = threadIdx.x;
    // kx: [33] float4 (k0,k1,k2,bias_sum). For z/r cols bias_sum = in_b + rec_b
    // (reset_after folds both); for hh cols only in_b (rec_b goes through r).
    for (int j = i; j < TH; j += BLOCK) {
        float bsum = bias[j] + ((j < 2 * HH) ? bias[TH + j] : 0.0f);
        ws[WS_KX + j * 4 + 0] = k[0 * TH + j];
        ws[WS_KX + j * 4 + 1] = k[1 * TH + j];
        ws[WS_KX + j * 4 + 2] = k[2 * TH + j];
        ws[WS_KX + j * 4 + 3] = bsum;
    }
    // rkp: transpose rk to [j][i], pad i to 12
    for (int idx = i; idx < TH * HP; idx += BLOCK) {
        int j = idx / HP, r = idx % HP;
        ws[WS_RKP + idx] = (r < HH) ? rk[r * TH + j] : 0.0f;
    }
    // rb: recurrent bias for hh columns
    for (int j = i; j < HP; j += BLOCK)
        ws[WS_RB + j] = (j < HH) ? bias[TH + 2 * HH + j] : 0.0f;
    // dwp: [121][8] padded
    for (int idx = i; idx < TT * HH * CP; idx += BLOCK) {
        int r = idx / CP, c = idx % CP;
        ws[WS_DWP + idx] = (c < CC) ? dw[r * CC + c] : 0.0f;
    }
    for (int c = i; c < CP; c += BLOCK)
        ws[WS_DBP + c] = (c < CC) ? db[c] : 0.0f;
}

__global__ __launch_bounds__(BLOCK, 4) void gru_main(
    const float* __restrict__ x,   // [B, T*F]
    const float* __restrict__ ws,  // packed weights
    float* __restrict__ out,       // [B, C]
    int Bt)
{
    __shared__ float smem[BLOCK * TF];  // 33 KB x-stage; reused for out-stage
    const int tid = threadIdx.x;
    const long long base = (long long)blockIdx.x * BLOCK;

    // coalesced x stage
    {
        const long long gbase = base * TF;
        const long long gmax = (long long)Bt * TF;
        #pragma unroll
        for (int i = 0; i < TF; ++i) {
            long long g = gbase + tid + i * BLOCK;
            smem[tid + i * BLOCK] = (g < gmax) ? x[g] : 0.0f;
        }
    }
    __syncthreads();

    const f4* __restrict__ KX = (const f4*)(ws + WS_KX);
    const f2* __restrict__ RK = (const f2*)(ws + WS_RKP);  // [33][6] f2
    const float* __restrict__ RB = ws + WS_RB;
    const f2* __restrict__ DW = (const f2*)(ws + WS_DWP);  // [121][4] f2
    const f2* __restrict__ DB = (const f2*)(ws + WS_DBP);

    f2 h2[6];
    #pragma unroll
    for (int p = 0; p < 6; ++p) h2[p] = f2{0.0f, 0.0f};
    f2 l2[4];
    #pragma unroll
    for (int q = 0; q < 4; ++q) l2[q] = DB[q];

    const float* xv = &smem[tid * TF];  // stride 33: conflict-free

    #pragma unroll 1
    for (int t = 0; t < TT; ++t) {
        const float x0 = xv[t * FF + 0];
        const float x1 = xv[t * FF + 1];
        const float x2 = xv[t * FF + 2];
        f2 hn2[6];

        #pragma unroll
        for (int j = 0; j < HH; ++j) {
            const f4 kz = KX[j];
            const f4 kr = KX[HH + j];
            const f4 kh = KX[2 * HH + j];
            f2 az = f2{0.0f, 0.0f}, ar = f2{0.0f, 0.0f}, ah = f2{0.0f, 0.0f};
            #pragma unroll
            for (int p = 0; p < 6; ++p) {
                az = __builtin_elementwise_fma(h2[p], RK[j * 6 + p], az);
                ar = __builtin_elementwise_fma(h2[p], RK[(HH + j) * 6 + p], ar);
                ah = __builtin_elementwise_fma(h2[p], RK[(2 * HH + j) * 6 + p], ah);
            }
            float sz = kz.w;
            sz = fmaf(x0, kz.x, sz); sz = fmaf(x1, kz.y, sz); sz = fmaf(x2, kz.z, sz);
            sz += az.x + az.y;
            float sr = kr.w;
            sr = fmaf(x0, kr.x, sr); sr = fmaf(x1, kr.y, sr); sr = fmaf(x2, kr.z, sr);
            sr += ar.x + ar.y;
            const float z = fast_sigmoid(sz);
            const float r = fast_sigmoid(sr);
            float xh = kh.w;
            xh = fmaf(x0, kh.x, xh); xh = fmaf(x1, kh.y, xh); xh = fmaf(x2, kh.z, xh);
            const float rh = RB[j] + ah.x + ah.y;
            const float hh = fast_tanh(fmaf(r, rh, xh));
            const float hj = (j & 1) ? h2[j >> 1].y : h2[j >> 1].x;
            const float hnew = hh + z * (hj - hh);  // z*h + (1-z)*hh
            if (j & 1) hn2[j >> 1].y = hnew; else hn2[j >> 1].x = hnew;
            // fused dense
            const int row = t * HH + j;
            const f2 hs = f2{hnew, hnew};
            #pragma unroll
            for (int q = 0; q < 4; ++q)
                l2[q] = __builtin_elementwise_fma(hs, DW[row * 4 + q], l2[q]);
        }
        hn2[5].y = 0.0f;  // keep pad lane of h at 0
        #pragma unroll
        for (int p = 0; p < 6; ++p) h2[p] = hn2[p];
    }

    // softmax over the 7 valid logits (pad col accumulated only zeros; exclude it)
    float lg[CC] = {l2[0].x, l2[0].y, l2[1].x, l2[1].y, l2[2].x, l2[2].y, l2[3].x};
    float m = lg[0];
    #pragma unroll
    for (int c = 1; c < CC; ++c) m = fmaxf(m, lg[c]);
    float s = 0.0f;
    float e[CC];
    #pragma unroll
    for (int c = 0; c < CC; ++c) {
        e[c] = __builtin_amdgcn_exp2f((lg[c] - m) * 1.44269504088896340736f);
        s += e[c];
    }
    const float inv = __builtin_amdgcn_rcpf(s);

    // staged coalesced writeback
    __syncthreads();
    #pragma unroll
    for (int c = 0; c < CC; ++c) smem[tid * CC + c] = e[c] * inv;
    __syncthreads();
    {
        const long long obase = base * CC;
        const long long omax = (long long)Bt * CC;
        #pragma unroll
        for (int i = 0; i < CC; ++i) {
            long long g = obase + tid + i * BLOCK;
            if (g < omax) out[g] = smem[tid + i * BLOCK];
        }
    }
}

extern "C" void kernel_launch(void* const* d_in, const int* in_sizes, int n_in,
                              void* d_out, int out_size, void* d_ws, size_t ws_size,
                              hipStream_t stream) {
    const float* x  = (const float*)d_in[0];
    const float* k  = (const float*)d_in[1];
    const float* rk = (const float*)d_in[2];
    const float* bi = (const float*)d_in[3];
    const float* dw = (const float*)d_in[4];
    const float* db = (const float*)d_in[5];
    float* out = (float*)d_out;
    float* ws  = (float*)d_ws;

    const int Bt = in_sizes[0] / TF;  // 1048576
    prep_weights<<<1, BLOCK, 0, stream>>>(k, rk, bi, dw, db, ws);
    const int grid = (Bt + BLOCK - 1) / BLOCK;
    gru_main<<<grid, BLOCK, 0, stream>>>(x, ws, out, Bt);
}

// Round 3
// 464.497 us; speedup vs baseline: 2.0926x; 1.3612x over previous
//
#include <hip/hip_runtime.h>

// Problem constants: B=1048576, T=11, F=3, H=11, C=7
#define TT 11
#define FF 3
#define HH 11
#define CC 7
#define TF 33      // T*F
#define BLOCK 256
#define XDW 22     // dwords per batch element in LDS x-stage (11 t * 2 dwords)

typedef _Float16 h2 __attribute__((ext_vector_type(2)));

// workspace dword offsets
#define WS_G   0      // [11][28]: per-gate block (see prep_weights)
#define WS_D   308    // [11][7][6]: dense f16 pairs per t, per col
#define WS_DB  770    // [7] f32 dense bias
// total 777 dwords

__device__ __forceinline__ float fdot2(h2 a, h2 b, float c) {
    // v_dot2_f32_f16: full-rate, fp32 accumulate
    return __builtin_amdgcn_fdot2(a, b, c, false);
}

__device__ __forceinline__ float fast_sigmoid(float a) {
    float t = __builtin_amdgcn_exp2f(-1.44269504088896340736f * a);
    return __builtin_amdgcn_rcpf(1.0f + t);
}
// tanh(a) = 2*sigmoid(2a) - 1 ; monotone-safe at +-inf, no NaN
__device__ __forceinline__ float fast_tanh(float a) {
    float t = __builtin_amdgcn_exp2f(-2.88539008177792681472f * a);
    return fmaf(2.0f, __builtin_amdgcn_rcpf(1.0f + t), -1.0f);
}

__global__ void prep_weights(const float* __restrict__ k,
                             const float* __restrict__ rk,
                             const float* __restrict__ bias,
                             const float* __restrict__ dw,
                             const float* __restrict__ db,
                             float* __restrict__ ws) {
    const int tid = threadIdx.x;
    // Per-gate 28-dword block: dot2-ready f16 pairs + f32 biases.
    //  [0..5]  z recurrent pairs (h0,h1)..(h10,0)
    //  [6]     z input pair (k0,k1)   [7] (k2, 0)
    //  [8]     z bias f32 (in+rec folded)
    //  [9..14] r recurrent pairs  [15],[16] r input  [17] r bias f32
    //  [18..23] h recurrent pairs
    //  [24],[25] h input pairs
    //  [26]    h recurrent bias f32 (inside r*)   [27] h input bias f32
    if (tid < HH) {
        const int j = tid;
        float* g = ws + WS_G + j * 28;
        h2* gp = (h2*)g;
        const int cz = j, cr = HH + j, ch = 2 * HH + j;
        #pragma unroll
        for (int p = 0; p < 6; ++p) {
            const int i0 = 2 * p, i1 = 2 * p + 1;
            h2 vz = {(_Float16)rk[i0 * TF + cz],
                     (_Float16)((i1 < HH) ? rk[i1 * TF + cz] : 0.0f)};
            gp[p] = vz;
            h2 vr = {(_Float16)rk[i0 * TF + cr],
                     (_Float16)((i1 < HH) ? rk[i1 * TF + cr] : 0.0f)};
            gp[9 + p] = vr;
            h2 vh = {(_Float16)rk[i0 * TF + ch],
                     (_Float16)((i1 < HH) ? rk[i1 * TF + ch] : 0.0f)};
            gp[18 + p] = vh;
        }
        h2 iz0 = {(_Float16)k[0 * TF + cz], (_Float16)k[1 * TF + cz]};
        h2 iz1 = {(_Float16)k[2 * TF + cz], (_Float16)0.0f};
        gp[6] = iz0; gp[7] = iz1;
        g[8] = bias[cz] + bias[TF + cz];
        h2 ir0 = {(_Float16)k[0 * TF + cr], (_Float16)k[1 * TF + cr]};
        h2 ir1 = {(_Float16)k[2 * TF + cr], (_Float16)0.0f};
        gp[15] = ir0; gp[16] = ir1;
        g[17] = bias[cr] + bias[TF + cr];
        h2 ih0 = {(_Float16)k[0 * TF + ch], (_Float16)k[1 * TF + ch]};
        h2 ih1 = {(_Float16)k[2 * TF + ch], (_Float16)0.0f};
        gp[24] = ih0; gp[25] = ih1;
        g[26] = bias[TF + ch];  // recurrent bias (multiplied by r)
        g[27] = bias[ch];       // input bias
    }
    // dense: pairs along j within each t, per output col c
    for (int idx = tid; idx < TT * CC; idx += BLOCK) {
        const int t = idx / CC, c = idx % CC;
        h2* d = (h2*)(ws + WS_D + t * 42 + c * 6);
        #pragma unroll
        for (int p = 0; p < 6; ++p) {
            const int j0 = 2 * p, j1 = 2 * p + 1;
            h2 v = {(_Float16)dw[(t * HH + j0) * CC + c],
                    (_Float16)((j1 < HH) ? dw[(t * HH + j1) * CC + c] : 0.0f)};
            d[p] = v;
        }
    }
    if (tid < CC) ws[WS_DB + tid] = db[tid];
}

__global__ __launch_bounds__(BLOCK, 6) void gru_main(
    const float* __restrict__ x,   // [B, T*F] f32
    const float* __restrict__ ws,  // packed weights
    float* __restrict__ out,       // [B, C]
    int Bt)
{
    __shared__ unsigned int sx[BLOCK * XDW];  // 22528 B -> 7 blocks/CU by LDS
    const int tid = threadIdx.x;
    const long long base = (long long)blockIdx.x * BLOCK;

    // ---- coalesced stage of x, converted+packed to f16 pairs (x0,x1),(x2,0) ----
    {
        const long long gbase = base * TF;
        const long long gmax = (long long)Bt * TF;
        unsigned short* sx16 = (unsigned short*)sx;
        #pragma unroll
        for (int i = 0; i < TF; ++i) {
            const int e = tid + i * BLOCK;           // flat idx in block tile
            const long long g = gbase + e;
            const float v = (g < gmax) ? x[g] : 0.0f;
            const int b = e / TF, r = e % TF;        // compiler emits magic-mul
            const int t = r / FF, s = r % FF;
            const unsigned short hv =
                __builtin_bit_cast(unsigned short, (_Float16)v);
            if (s == 2)
                sx[b * XDW + 2 * t + 1] = (unsigned int)hv;  // (x2, 0): hi half zeroed
            else
                sx16[(b * XDW + 2 * t) * 2 + s] = hv;        // byte-masked b16 write
        }
    }
    __syncthreads();

    const uint2* xrow = (const uint2*)(sx + tid * XDW);

    float hf[HH];
    #pragma unroll
    for (int j = 0; j < HH; ++j) hf[j] = 0.0f;
    h2 hp[6];
    #pragma unroll
    for (int p = 0; p < 6; ++p) { h2 zz = {(_Float16)0.0f, (_Float16)0.0f}; hp[p] = zz; }
    float lg[CC];
    #pragma unroll
    for (int c = 0; c < CC; ++c) lg[c] = ws[WS_DB + c];

    #pragma unroll 1
    for (int t = 0; t < TT; ++t) {
        const uint2 xw = xrow[t];                 // one ds_read_b64
        const h2 xp0 = __builtin_bit_cast(h2, xw.x);
        const h2 xp1 = __builtin_bit_cast(h2, xw.y);

        #pragma unroll
        for (int j = 0; j < HH; ++j) {
            const float* g = ws + WS_G + j * 28;
            const h2* gp = (const h2*)g;
            float az = g[8];
            float ar = g[17];
            float rh = g[26];
            float xh = g[27];
            #pragma unroll
            for (int p = 0; p < 6; ++p) {
                az = fdot2(hp[p], gp[p], az);
                ar = fdot2(hp[p], gp[9 + p], ar);
                rh = fdot2(hp[p], gp[18 + p], rh);
            }
            az = fdot2(xp0, gp[6], az);   az = fdot2(xp1, gp[7], az);
            ar = fdot2(xp0, gp[15], ar);  ar = fdot2(xp1, gp[16], ar);
            xh = fdot2(xp0, gp[24], xh);  xh = fdot2(xp1, gp[25], xh);
            const float z = fast_sigmoid(az);
            const float r = fast_sigmoid(ar);
            const float hh = fast_tanh(fmaf(r, rh, xh));
            hf[j] = hh + z * (hf[j] - hh);   // z*h + (1-z)*hh
        }
        // repack h -> f16 pairs (v_cvt_pkrtz x6)
        #pragma unroll
        for (int p = 0; p < 5; ++p) {
            h2 v = {(_Float16)hf[2 * p], (_Float16)hf[2 * p + 1]};
            hp[p] = v;
        }
        { h2 v = {(_Float16)hf[10], (_Float16)0.0f}; hp[5] = v; }

        // fused dense: logits += h_t @ dw_t (fp32 accum via dot2)
        const h2* dd = (const h2*)(ws + WS_D + t * 42);
        #pragma unroll
        for (int c = 0; c < CC; ++c) {
            float acc = lg[c];
            #pragma unroll
            for (int p = 0; p < 6; ++p) acc = fdot2(hp[p], dd[c * 6 + p], acc);
            lg[c] = acc;
        }
    }

    // ---- softmax ----
    float m = lg[0];
    #pragma unroll
    for (int c = 1; c < CC; ++c) m = fmaxf(m, lg[c]);
    float s = 0.0f;
    float e[CC];
    #pragma unroll
    for (int c = 0; c < CC; ++c) {
        e[c] = __builtin_amdgcn_exp2f((lg[c] - m) * 1.44269504088896340736f);
        s += e[c];
    }
    const float inv = __builtin_amdgcn_rcpf(s);

    // ---- staged coalesced writeback (reuse sx as float buffer) ----
    __syncthreads();
    float* sf = (float*)sx;
    #pragma unroll
    for (int c = 0; c < CC; ++c) sf[tid * CC + c] = e[c] * inv;  // stride 7: conflict-free
    __syncthreads();
    {
        const long long obase = base * CC;
        const long long omax = (long long)Bt * CC;
        #pragma unroll
        for (int i = 0; i < CC; ++i) {
            long long g = obase + tid + i * BLOCK;
            if (g < omax) out[g] = sf[tid + i * BLOCK];
        }
    }
}

extern "C" void kernel_launch(void* const* d_in, const int* in_sizes, int n_in,
                              void* d_out, int out_size, void* d_ws, size_t ws_size,
                              hipStream_t stream) {
    const float* x  = (const float*)d_in[0];
    const float* k  = (const float*)d_in[1];
    const float* rk = (const float*)d_in[2];
    const float* bi = (const float*)d_in[3];
    const float* dw = (const float*)d_in[4];
    const float* db = (const float*)d_in[5];
    float* out = (float*)d_out;
    float* ws  = (float*)d_ws;

    const int Bt = in_sizes[0] / TF;  // 1048576
    prep_weights<<<1, BLOCK, 0, stream>>>(k, rk, bi, dw, db, ws);
    const int grid = (Bt + BLOCK - 1) / BLOCK;
    gru_main<<<grid, BLOCK, 0, stream>>>(x, ws, out, Bt);
}